// Round 1
// baseline (744.380 us; speedup 1.0000x reference)
//
#include <hip/hip_runtime.h>
#include <stdint.h>

#define NB 32
#define CC 256
#define HH 56
#define WW 56
#define PP (HH*WW)          // 3136
#define NPIX (NB*PP)        // 100352
#define W32 8               // 256 channels / 32 bits
#define KEPS 1e-5f

// ---------------- BN stats: per-(n,c) plane partial sums -> atomics ----------------
__global__ void k_stats(const float* __restrict__ x, float* __restrict__ ssum, float* __restrict__ ssq) {
    int plane = blockIdx.x;               // n*CC + c
    int c = plane & (CC - 1);
    const float* xp = x + (size_t)plane * PP;
    float s = 0.f, q = 0.f;
    for (int i = threadIdx.x; i < PP; i += blockDim.x) {
        float v = xp[i]; s += v; q = fmaf(v, v, q);
    }
#pragma unroll
    for (int off = 32; off; off >>= 1) { s += __shfl_down(s, off); q += __shfl_down(q, off); }
    __shared__ float ls[4], lq[4];
    int wv = threadIdx.x >> 6, ln = threadIdx.x & 63;
    if (ln == 0) { ls[wv] = s; lq[wv] = q; }
    __syncthreads();
    if (threadIdx.x == 0) {
        float S = 0.f, Q = 0.f;
        for (int w = 0; w < 4; ++w) { S += ls[w]; Q += lq[w]; }
        atomicAdd(&ssum[c], S); atomicAdd(&ssq[c], Q);
    }
}

// ---------------- finalize BN: scale = g/sqrt(var+eps), bias = beta - m*scale ------
__global__ void k_fin(const float* __restrict__ ssum, const float* __restrict__ ssq,
                      const float* __restrict__ gamma, const float* __restrict__ beta,
                      float* __restrict__ scale, float* __restrict__ bias) {
    int c = threadIdx.x;
    float m   = ssum[c] * (1.0f / NPIX);
    float var = fmaf(-m, m, ssq[c] * (1.0f / NPIX));
    float s   = gamma[c] / sqrtf(var + KEPS);
    scale[c] = s;
    bias[c]  = fmaf(-m, s, beta[c]);
}

// ---------------- weight prep: sign-pack + alpha (one wave per output channel) -----
__global__ void k_wprep(const float* __restrict__ w1, const float* __restrict__ w2,
                        uint32_t* __restrict__ wb1, uint32_t* __restrict__ wb2,
                        float* __restrict__ al1, float* __restrict__ al2) {
    int o2 = blockIdx.x;                  // 0..511
    const float* w = (o2 < CC) ? w1 : w2;
    uint32_t* wb   = (o2 < CC) ? wb1 : wb2;
    float* al      = (o2 < CC) ? al1 : al2;
    int o = o2 & (CC - 1);
    int lane = threadIdx.x;               // 64
    float asum = 0.f;
    for (int cg = 0; cg < 4; ++cg) {
        int c = cg * 64 + lane;
        const float* wp = w + ((size_t)o * CC + c) * 9;
        for (int t = 0; t < 9; ++t) {
            float wv = wp[t];
            asum += fabsf(wv);
            unsigned long long m = __ballot(wv >= 0.0f);
            if (lane == 0) {
                wb[(o * 9 + t) * W32 + cg * 2]     = (uint32_t)m;
                wb[(o * 9 + t) * W32 + cg * 2 + 1] = (uint32_t)(m >> 32);
            }
        }
    }
#pragma unroll
    for (int off = 32; off; off >>= 1) asum += __shfl_down(asum, off);
    if (lane == 0) al[o] = asum * (1.0f / 2304.0f);
}

// ---------------- BN1 apply + sign pack + channel-mean a1 --------------------------
// thread handles one (pixel, quarter-of-channels); 4 threads/pixel, adjacent lanes
__global__ void k_bn1pack(const float* __restrict__ x, const float* __restrict__ scale,
                          const float* __restrict__ bias, uint32_t* __restrict__ xbits,
                          float* __restrict__ a) {
    int gid = blockIdx.x * 256 + threadIdx.x;    // NPIX*4 total
    int pix = gid >> 2;
    int q   = gid & 3;
    int n = pix / PP;
    int p = pix - n * PP;
    const float* xp = x + (size_t)n * CC * PP + p;
    uint32_t w0 = 0, w1 = 0;
    float asum = 0.f;
#pragma unroll
    for (int i = 0; i < 64; ++i) {
        int c = (q << 6) + i;
        float v = xp[(size_t)c * PP];
        float bnv = fmaf(v, scale[c], bias[c]);
        asum += bnv;
        uint32_t bit = (bnv >= 0.0f) ? 1u : 0u;
        if (i < 32) w0 |= bit << i; else w1 |= bit << (i - 32);
    }
    xbits[(size_t)pix * W32 + q * 2]     = w0;
    xbits[(size_t)pix * W32 + q * 2 + 1] = w1;
    asum += __shfl_xor(asum, 1);
    asum += __shfl_xor(asum, 2);
    if (q == 0) a[pix] = asum * (1.0f / CC);
}

// ---------------- BN2 apply (recompute val from int16 conv) + pack + a2 ------------
__global__ void k_bn2pack(const short* __restrict__ ci, const float* __restrict__ alpha1,
                          const float* __restrict__ k1, const float* __restrict__ scale,
                          const float* __restrict__ bias, uint32_t* __restrict__ xbits,
                          float* __restrict__ a) {
    int gid = blockIdx.x * 256 + threadIdx.x;
    int pix = gid >> 2;
    int q   = gid & 3;
    int n = pix / PP;
    int p = pix - n * PP;
    const short* cp = ci + (size_t)n * CC * PP + p;
    float kv = k1[pix];
    uint32_t w0 = 0, w1 = 0;
    float asum = 0.f;
#pragma unroll
    for (int i = 0; i < 64; ++i) {
        int o = (q << 6) + i;
        float val = fmaxf(alpha1[o] * kv * (float)cp[(size_t)o * PP], 0.f);
        float bnv = fmaf(val, scale[o], bias[o]);
        asum += bnv;
        uint32_t bit = (bnv >= 0.0f) ? 1u : 0u;
        if (i < 32) w0 |= bit << i; else w1 |= bit << (i - 32);
    }
    xbits[(size_t)pix * W32 + q * 2]     = w0;
    xbits[(size_t)pix * W32 + q * 2 + 1] = w1;
    asum += __shfl_xor(asum, 1);
    asum += __shfl_xor(asum, 2);
    if (q == 0) a[pix] = asum * (1.0f / CC);
}

// ---------------- 3x3 box filter (zero padded, /9) ---------------------------------
__global__ void k_box(const float* __restrict__ a, float* __restrict__ k) {
    int gid = blockIdx.x * 256 + threadIdx.x;    // NPIX
    int n = gid / PP;
    int p = gid - n * PP;
    int h = p / WW, w = p - (p / WW) * WW;
    const float* ap = a + (size_t)n * PP;
    float s = 0.f;
    for (int dr = -1; dr <= 1; ++dr) {
        int hh = h + dr;
        if (hh < 0 || hh >= HH) continue;
        for (int dc = -1; dc <= 1; ++dc) {
            int ww2 = w + dc;
            if (ww2 < 0 || ww2 >= WW) continue;
            s += ap[hh * WW + ww2];
        }
    }
    k[gid] = s * (1.0f / 9.0f);
}

// ---------------- binary conv core: xor+popcount over bit-packed channels ----------
// block: 448 threads = 8 rows x 56 cols of pixels, fixed n, 128 output channels.
template<bool FIRST>
__global__ __launch_bounds__(448) void k_conv(
    const uint32_t* __restrict__ xbits, const uint32_t* __restrict__ wbits,
    const float* __restrict__ alpha, const float* __restrict__ kmap,
    short* __restrict__ out_i16, float* __restrict__ ssum, float* __restrict__ ssq,
    const float* __restrict__ ident, float* __restrict__ outf)
{
    constexpr int TH = 8, TO = 128;
    __shared__ uint32_t lds_x[(TH + 2) * WW * W32];   // 4480 u32 = 17.9 KB
    __shared__ uint32_t lds_w[TO * 9 * W32];          // 9216 u32 = 36.9 KB
    __shared__ float lds_s[7][TO][2];                 // 7 KB (stats, FIRST only)

    int b = blockIdx.x;
    int ob = b & 1, hb = (b >> 1) % 7, n = b / 14;
    int h0 = hb * TH, o0 = ob * TO;
    int tid = threadIdx.x;

    {   // stage weight bits (contiguous copy)
        const uint4* wsrc = (const uint4*)(wbits + (size_t)o0 * 9 * W32);
        uint4* wdst = (uint4*)lds_w;
        for (int i = tid; i < TO * 9 * W32 / 4; i += 448) wdst[i] = wsrc[i];
    }
    {   // stage x bits rows h0-1 .. h0+TH (zero halo)
        uint4* xdst = (uint4*)lds_x;
        for (int i = tid; i < (TH + 2) * WW * 2; i += 448) {
            int r = i / (WW * 2);
            int j = i - r * (WW * 2);
            int gr = h0 - 1 + r;
            uint4 v = make_uint4(0u, 0u, 0u, 0u);
            if (gr >= 0 && gr < HH)
                v = ((const uint4*)(xbits + ((size_t)n * PP + (size_t)gr * WW) * W32))[j];
            xdst[i] = v;
        }
    }
    if (FIRST) {
        float* sp = (float*)lds_s;
        for (int i = tid; i < 7 * TO * 2; i += 448) sp[i] = 0.f;
    }
    __syncthreads();

    int row = tid / WW, col = tid - (tid / WW) * WW;
    int h = h0 + row;
    size_t gp = (size_t)n * PP + (size_t)h * WW + col;
    float kv = kmap[gp];

    // pull this pixel's 3x3 window of bit words into registers (72 u32)
    uint32_t xw[9][W32];
    int vmask = 0, nvalid = 0;
#pragma unroll
    for (int t = 0; t < 9; ++t) {
        int dr = t / 3 - 1, dc = t % 3 - 1;
        int cc = col + dc;
        bool v = (cc >= 0) && (cc < WW) && (h + dr >= 0) && (h + dr < HH);
        if (v) { vmask |= 1 << t; nvalid++; }
        int ccc = cc < 0 ? 0 : (cc >= WW ? WW - 1 : cc);
        int base = ((row + 1 + dr) * WW + ccc) * W32;
#pragma unroll
        for (int wd = 0; wd < W32; ++wd) xw[t][wd] = lds_x[base + wd];
    }

    int wavei = tid >> 6;

    for (int oi = 0; oi < TO; ++oi) {
        const uint4* wr = (const uint4*)(lds_w + oi * 9 * W32);
        int cs = 0;
#pragma unroll
        for (int t = 0; t < 9; ++t) {
            uint4 wa = wr[2 * t], wb = wr[2 * t + 1];
            int cnt;
            cnt  = __popc(xw[t][0] ^ wa.x);
            cnt += __popc(xw[t][1] ^ wa.y);
            cnt += __popc(xw[t][2] ^ wa.z);
            cnt += __popc(xw[t][3] ^ wa.w);
            cnt += __popc(xw[t][4] ^ wb.x);
            cnt += __popc(xw[t][5] ^ wb.y);
            cnt += __popc(xw[t][6] ^ wb.z);
            cnt += __popc(xw[t][7] ^ wb.w);
            cs += (vmask & (1 << t)) ? cnt : 0;
        }
        int acc = 256 * nvalid - 2 * cs;
        int o = o0 + oi;
        float res = alpha[o] * kv * (float)acc;
        size_t oidx = ((size_t)n * CC + o) * PP + (size_t)h * WW + col;
        if (FIRST) {
            out_i16[oidx] = (short)acc;
            float val = fmaxf(res, 0.f);
            float s = val, q = val * val;
#pragma unroll
            for (int off = 32; off; off >>= 1) { s += __shfl_down(s, off); q += __shfl_down(q, off); }
            if ((tid & 63) == 0) {
                lds_s[wavei][oi][0] += s;
                lds_s[wavei][oi][1] += q;
            }
        } else {
            outf[oidx] = fmaxf(res + ident[oidx], 0.f);
        }
    }

    if (FIRST) {
        __syncthreads();
        for (int i = tid; i < TO; i += 448) {
            float s = 0.f, q = 0.f;
#pragma unroll
            for (int wv = 0; wv < 7; ++wv) { s += lds_s[wv][i][0]; q += lds_s[wv][i][1]; }
            atomicAdd(&ssum[o0 + i], s);
            atomicAdd(&ssq[o0 + i], q);
        }
    }
}

extern "C" void kernel_launch(void* const* d_in, const int* in_sizes, int n_in,
                              void* d_out, int out_size, void* d_ws, size_t ws_size,
                              hipStream_t stream)
{
    const float* x  = (const float*)d_in[0];
    const float* g1 = (const float*)d_in[1];
    const float* b1 = (const float*)d_in[2];
    const float* w1 = (const float*)d_in[3];
    const float* g2 = (const float*)d_in[4];
    const float* b2 = (const float*)d_in[5];
    const float* w2 = (const float*)d_in[6];
    float* out = (float*)d_out;

    char* ws = (char*)d_ws;
    float* s1sum  = (float*)(ws + 0);
    float* s1sq   = (float*)(ws + 1024);
    float* s2sum  = (float*)(ws + 2048);
    float* s2sq   = (float*)(ws + 3072);
    float* scale1 = (float*)(ws + 4096);
    float* bias1  = (float*)(ws + 5120);
    float* scale2 = (float*)(ws + 6144);
    float* bias2  = (float*)(ws + 7168);
    float* alpha1 = (float*)(ws + 8192);
    float* alpha2 = (float*)(ws + 9216);
    uint32_t* wbits1 = (uint32_t*)(ws + 10240);           // 73728 B
    uint32_t* wbits2 = (uint32_t*)(ws + 83968);           // 73728 B
    float* a1 = (float*)(ws + 157696);                    // 401408 B
    float* k1 = (float*)(ws + 559104);
    float* a2 = (float*)(ws + 960512);
    float* k2 = (float*)(ws + 1361920);
    uint32_t* xbits1 = (uint32_t*)(ws + 1763328);         // 3211264 B
    uint32_t* xbits2 = (uint32_t*)(ws + 4974592);         // 3211264 B
    short* ci = (short*)(ws + 8185856);                   // 51380224 B (int16 conv1 sums)

    hipMemsetAsync(ws, 0, 4096, stream);                  // zero stat accumulators
    k_wprep<<<2 * CC, 64, 0, stream>>>(w1, w2, wbits1, wbits2, alpha1, alpha2);
    k_stats<<<NB * CC, 256, 0, stream>>>(x, s1sum, s1sq);
    k_fin<<<1, 256, 0, stream>>>(s1sum, s1sq, g1, b1, scale1, bias1);
    k_bn1pack<<<NPIX * 4 / 256, 256, 0, stream>>>(x, scale1, bias1, xbits1, a1);
    k_box<<<NPIX / 256, 256, 0, stream>>>(a1, k1);
    k_conv<true><<<448, 448, 0, stream>>>(xbits1, wbits1, alpha1, k1, ci, s2sum, s2sq, nullptr, nullptr);
    k_fin<<<1, 256, 0, stream>>>(s2sum, s2sq, g2, b2, scale2, bias2);
    k_bn2pack<<<NPIX * 4 / 256, 256, 0, stream>>>(ci, alpha1, k1, scale2, bias2, xbits2, a2);
    k_box<<<NPIX / 256, 256, 0, stream>>>(a2, k2);
    k_conv<false><<<448, 448, 0, stream>>>(xbits2, wbits2, alpha2, k2, nullptr, nullptr, nullptr, x, out);
}

// Round 2
// 653.244 us; speedup vs baseline: 1.1395x; 1.1395x over previous
//
#include <hip/hip_runtime.h>
#include <stdint.h>

#define NB 32
#define CC 256
#define HH 56
#define WW 56
#define PP (HH*WW)          // 3136
#define NPIX (NB*PP)        // 100352
#define W32 8               // 256 channels / 32 bits
#define KEPS 1e-5f

// ---------------- BN stats: per-(n,c) plane partial sums -> atomics ----------------
__global__ void k_stats(const float* __restrict__ x, float* __restrict__ ssum, float* __restrict__ ssq) {
    int plane = blockIdx.x;               // n*CC + c
    int c = plane & (CC - 1);
    const float* xp = x + (size_t)plane * PP;
    float s = 0.f, q = 0.f;
    for (int i = threadIdx.x; i < PP; i += blockDim.x) {
        float v = xp[i]; s += v; q = fmaf(v, v, q);
    }
#pragma unroll
    for (int off = 32; off; off >>= 1) { s += __shfl_down(s, off); q += __shfl_down(q, off); }
    __shared__ float ls[4], lq[4];
    int wv = threadIdx.x >> 6, ln = threadIdx.x & 63;
    if (ln == 0) { ls[wv] = s; lq[wv] = q; }
    __syncthreads();
    if (threadIdx.x == 0) {
        float S = 0.f, Q = 0.f;
        for (int w = 0; w < 4; ++w) { S += ls[w]; Q += lq[w]; }
        atomicAdd(&ssum[c], S); atomicAdd(&ssq[c], Q);
    }
}

// ---- BN2 stats from int16 conv sums: val = relu(alpha1[o]*k1[pix]*acc) ------------
__global__ void k_stats2(const short* __restrict__ ci, const float* __restrict__ alpha1,
                         const float* __restrict__ k1, float* __restrict__ ssum, float* __restrict__ ssq) {
    int plane = blockIdx.x;               // n*CC + o
    int o = plane & (CC - 1);
    int n = plane >> 8;
    const short* cp = ci + (size_t)plane * PP;
    const float* kp = k1 + (size_t)n * PP;
    float al = alpha1[o];
    float s = 0.f, q = 0.f;
    for (int i = threadIdx.x; i < PP; i += blockDim.x) {
        float v = fmaxf(al * kp[i] * (float)cp[i], 0.f);
        s += v; q = fmaf(v, v, q);
    }
#pragma unroll
    for (int off = 32; off; off >>= 1) { s += __shfl_down(s, off); q += __shfl_down(q, off); }
    __shared__ float ls[4], lq[4];
    int wv = threadIdx.x >> 6, ln = threadIdx.x & 63;
    if (ln == 0) { ls[wv] = s; lq[wv] = q; }
    __syncthreads();
    if (threadIdx.x == 0) {
        float S = 0.f, Q = 0.f;
        for (int w = 0; w < 4; ++w) { S += ls[w]; Q += lq[w]; }
        atomicAdd(&ssum[o], S); atomicAdd(&ssq[o], Q);
    }
}

// ---------------- finalize BN: scale = g/sqrt(var+eps), bias = beta - m*scale ------
__global__ void k_fin(const float* __restrict__ ssum, const float* __restrict__ ssq,
                      const float* __restrict__ gamma, const float* __restrict__ beta,
                      float* __restrict__ scale, float* __restrict__ bias) {
    int c = threadIdx.x;
    float m   = ssum[c] * (1.0f / NPIX);
    float var = fmaf(-m, m, ssq[c] * (1.0f / NPIX));
    float s   = gamma[c] / sqrtf(var + KEPS);
    scale[c] = s;
    bias[c]  = fmaf(-m, s, beta[c]);
}

// ---------------- weight prep: sign-pack + alpha (one wave per output channel) -----
__global__ void k_wprep(const float* __restrict__ w1, const float* __restrict__ w2,
                        uint32_t* __restrict__ wb1, uint32_t* __restrict__ wb2,
                        float* __restrict__ al1, float* __restrict__ al2) {
    int o2 = blockIdx.x;                  // 0..511
    const float* w = (o2 < CC) ? w1 : w2;
    uint32_t* wb   = (o2 < CC) ? wb1 : wb2;
    float* al      = (o2 < CC) ? al1 : al2;
    int o = o2 & (CC - 1);
    int lane = threadIdx.x;               // 64
    float asum = 0.f;
    for (int cg = 0; cg < 4; ++cg) {
        int c = cg * 64 + lane;
        const float* wp = w + ((size_t)o * CC + c) * 9;
        for (int t = 0; t < 9; ++t) {
            float wv = wp[t];
            asum += fabsf(wv);
            unsigned long long m = __ballot(wv >= 0.0f);
            if (lane == 0) {
                wb[(o * 9 + t) * W32 + cg * 2]     = (uint32_t)m;
                wb[(o * 9 + t) * W32 + cg * 2 + 1] = (uint32_t)(m >> 32);
            }
        }
    }
#pragma unroll
    for (int off = 32; off; off >>= 1) asum += __shfl_down(asum, off);
    if (lane == 0) al[o] = asum * (1.0f / 2304.0f);
}

// ---------------- BN1 apply + sign pack + channel-mean a1 --------------------------
// block 256 thr = 4 waves; each wave covers the SAME 64 consecutive pixels,
// wave w handles channels [w*64, w*64+64). Loads are 256B contiguous per instr.
__global__ void k_bn1pack(const float* __restrict__ x, const float* __restrict__ scale,
                          const float* __restrict__ bias, uint32_t* __restrict__ xbits,
                          float* __restrict__ a) {
    int lane = threadIdx.x & 63, wv = threadIdx.x >> 6;
    int n = blockIdx.x / 49;                        // 3136 = 49*64 pixels per image
    int pix = blockIdx.x * 64 + lane;
    int p = pix - n * PP;
    const float* xp = x + (size_t)n * CC * PP + p;
    uint32_t b0 = 0, b1 = 0;
    float asum = 0.f;
#pragma unroll
    for (int i = 0; i < 64; ++i) {
        int c = (wv << 6) + i;
        float v = xp[(size_t)c * PP];
        float bnv = fmaf(v, scale[c], bias[c]);
        asum += bnv;
        uint32_t bit = (bnv >= 0.0f) ? 1u : 0u;
        if (i < 32) b0 |= bit << i; else b1 |= bit << (i - 32);
    }
    ((uint2*)xbits)[(size_t)pix * 4 + wv] = make_uint2(b0, b1);
    __shared__ float lsum[4][64];
    lsum[wv][lane] = asum;
    __syncthreads();
    if (wv == 0)
        a[pix] = (lsum[0][lane] + lsum[1][lane] + lsum[2][lane] + lsum[3][lane]) * (1.0f / CC);
}

// ---------------- BN2 apply (recompute val from int16 conv) + pack + a2 ------------
__global__ void k_bn2pack(const short* __restrict__ ci, const float* __restrict__ alpha1,
                          const float* __restrict__ k1, const float* __restrict__ scale,
                          const float* __restrict__ bias, uint32_t* __restrict__ xbits,
                          float* __restrict__ a) {
    int lane = threadIdx.x & 63, wv = threadIdx.x >> 6;
    int n = blockIdx.x / 49;
    int pix = blockIdx.x * 64 + lane;
    int p = pix - n * PP;
    const short* cp = ci + (size_t)n * CC * PP + p;
    float kv = k1[pix];
    uint32_t b0 = 0, b1 = 0;
    float asum = 0.f;
#pragma unroll
    for (int i = 0; i < 64; ++i) {
        int o = (wv << 6) + i;
        float val = fmaxf(alpha1[o] * kv * (float)cp[(size_t)o * PP], 0.f);
        float bnv = fmaf(val, scale[o], bias[o]);
        asum += bnv;
        uint32_t bit = (bnv >= 0.0f) ? 1u : 0u;
        if (i < 32) b0 |= bit << i; else b1 |= bit << (i - 32);
    }
    ((uint2*)xbits)[(size_t)pix * 4 + wv] = make_uint2(b0, b1);
    __shared__ float lsum[4][64];
    lsum[wv][lane] = asum;
    __syncthreads();
    if (wv == 0)
        a[pix] = (lsum[0][lane] + lsum[1][lane] + lsum[2][lane] + lsum[3][lane]) * (1.0f / CC);
}

// ---------------- 3x3 box filter (zero padded, /9) ---------------------------------
__global__ void k_box(const float* __restrict__ a, float* __restrict__ k) {
    int gid = blockIdx.x * 256 + threadIdx.x;    // NPIX
    int n = gid / PP;
    int p = gid - n * PP;
    int h = p / WW, w = p - (p / WW) * WW;
    const float* ap = a + (size_t)n * PP;
    float s = 0.f;
    for (int dr = -1; dr <= 1; ++dr) {
        int hh = h + dr;
        if (hh < 0 || hh >= HH) continue;
        for (int dc = -1; dc <= 1; ++dc) {
            int ww2 = w + dc;
            if (ww2 < 0 || ww2 >= WW) continue;
            s += ap[hh * WW + ww2];
        }
    }
    k[gid] = s * (1.0f / 9.0f);
}

// ---------------- binary conv core: xor+popcount, weights via SGPR (s_load) --------
// block: 448 threads = 8 rows x 56 cols of pixels, fixed n, TO=64 output channels.
// Weights are wave-uniform -> compiler emits s_load from scalar cache; no LDS reads
// in the inner loop (v_xor_b32 vgpr,sgpr + v_bcnt accumulate).
template<bool FIRST>
__global__ __launch_bounds__(448) void k_conv(
    const uint32_t* __restrict__ xbits, const uint32_t* __restrict__ wbits,
    const float* __restrict__ alpha, const float* __restrict__ kmap,
    short* __restrict__ out_i16,
    const float* __restrict__ ident, float* __restrict__ outf)
{
    constexpr int TH = 8, TO = 64;
    __shared__ uint32_t lds_x[(TH + 2) * WW * W32];   // 4480 u32 = 17.9 KB

    int b = blockIdx.x;
    int ob = b & 3, hb = (b >> 2) % 7, n = b / 28;
    int h0 = hb * TH, o0 = ob * TO;
    int tid = threadIdx.x;

    {   // stage x bits rows h0-1 .. h0+TH (zero halo)
        uint4* xdst = (uint4*)lds_x;
        for (int i = tid; i < (TH + 2) * WW * 2; i += 448) {
            int r = i / (WW * 2);
            int j = i - r * (WW * 2);
            int gr = h0 - 1 + r;
            uint4 v = make_uint4(0u, 0u, 0u, 0u);
            if (gr >= 0 && gr < HH)
                v = ((const uint4*)(xbits + ((size_t)n * PP + (size_t)gr * WW) * W32))[j];
            xdst[i] = v;
        }
    }
    __syncthreads();

    int row = tid / WW, col = tid - (tid / WW) * WW;
    int h = h0 + row;
    size_t gp = (size_t)n * PP + (size_t)h * WW + col;
    float kv = FIRST ? 0.f : kmap[gp];

    // pull this pixel's 3x3 window of bit words into registers (72 u32)
    uint32_t xw[9][W32];
    int vmask = 0, nvalid = 0;
#pragma unroll
    for (int t = 0; t < 9; ++t) {
        int dr = t / 3 - 1, dc = t % 3 - 1;
        int cc = col + dc;
        bool v = (cc >= 0) && (cc < WW) && (h + dr >= 0) && (h + dr < HH);
        if (v) { vmask |= 1 << t; nvalid++; }
        int ccc = cc < 0 ? 0 : (cc >= WW ? WW - 1 : cc);
        int base = ((row + 1 + dr) * WW + ccc) * W32;
#pragma unroll
        for (int wd = 0; wd < W32; ++wd) xw[t][wd] = lds_x[base + wd];
    }

    for (int oi = 0; oi < TO; ++oi) {
        int o = o0 + oi;
        const uint32_t* __restrict__ wr = wbits + (size_t)o * 9 * W32;  // uniform addr
        int cs = 0;
#pragma unroll
        for (int t = 0; t < 9; ++t) {
            int cnt = 0;
#pragma unroll
            for (int wd = 0; wd < W32; ++wd)
                cnt += __popc(xw[t][wd] ^ wr[t * W32 + wd]);
            cs += ((vmask >> t) & 1) ? cnt : 0;
        }
        int acc = 256 * nvalid - 2 * cs;
        size_t oidx = ((size_t)n * CC + o) * PP + (size_t)h * WW + col;
        if (FIRST) {
            out_i16[oidx] = (short)acc;
        } else {
            float res = alpha[o] * kv * (float)acc;
            outf[oidx] = fmaxf(res + ident[oidx], 0.f);
        }
    }
}

extern "C" void kernel_launch(void* const* d_in, const int* in_sizes, int n_in,
                              void* d_out, int out_size, void* d_ws, size_t ws_size,
                              hipStream_t stream)
{
    const float* x  = (const float*)d_in[0];
    const float* g1 = (const float*)d_in[1];
    const float* b1 = (const float*)d_in[2];
    const float* w1 = (const float*)d_in[3];
    const float* g2 = (const float*)d_in[4];
    const float* b2 = (const float*)d_in[5];
    const float* w2 = (const float*)d_in[6];
    float* out = (float*)d_out;

    char* ws = (char*)d_ws;
    float* s1sum  = (float*)(ws + 0);
    float* s1sq   = (float*)(ws + 1024);
    float* s2sum  = (float*)(ws + 2048);
    float* s2sq   = (float*)(ws + 3072);
    float* scale1 = (float*)(ws + 4096);
    float* bias1  = (float*)(ws + 5120);
    float* scale2 = (float*)(ws + 6144);
    float* bias2  = (float*)(ws + 7168);
    float* alpha1 = (float*)(ws + 8192);
    float* alpha2 = (float*)(ws + 9216);
    uint32_t* wbits1 = (uint32_t*)(ws + 10240);           // 73728 B
    uint32_t* wbits2 = (uint32_t*)(ws + 83968);           // 73728 B
    float* a1 = (float*)(ws + 157696);                    // 401408 B
    float* k1 = (float*)(ws + 559104);
    float* a2 = (float*)(ws + 960512);
    float* k2 = (float*)(ws + 1361920);
    uint32_t* xbits1 = (uint32_t*)(ws + 1763328);         // 3211264 B
    uint32_t* xbits2 = (uint32_t*)(ws + 4974592);         // 3211264 B
    short* ci = (short*)(ws + 8185856);                   // 51380224 B (int16 conv1 sums)

    hipMemsetAsync(ws, 0, 4096, stream);                  // zero stat accumulators
    k_wprep<<<2 * CC, 64, 0, stream>>>(w1, w2, wbits1, wbits2, alpha1, alpha2);
    k_stats<<<NB * CC, 256, 0, stream>>>(x, s1sum, s1sq);
    k_fin<<<1, 256, 0, stream>>>(s1sum, s1sq, g1, b1, scale1, bias1);
    k_bn1pack<<<NPIX / 64, 256, 0, stream>>>(x, scale1, bias1, xbits1, a1);
    k_box<<<NPIX / 256, 256, 0, stream>>>(a1, k1);
    k_conv<true><<<NB * 7 * 4, 448, 0, stream>>>(xbits1, wbits1, nullptr, nullptr, ci, nullptr, nullptr);
    k_stats2<<<NB * CC, 256, 0, stream>>>(ci, alpha1, k1, s2sum, s2sq);
    k_fin<<<1, 256, 0, stream>>>(s2sum, s2sq, g2, b2, scale2, bias2);
    k_bn2pack<<<NPIX / 64, 256, 0, stream>>>(ci, alpha1, k1, scale2, bias2, xbits2, a2);
    k_box<<<NPIX / 256, 256, 0, stream>>>(a2, k2);
    k_conv<false><<<NB * 7 * 4, 448, 0, stream>>>(xbits2, wbits2, alpha2, k2, nullptr, x, out);
}